// Round 1
// baseline (449.526 us; speedup 1.0000x reference)
//
#include <hip/hip_runtime.h>
#include <stdint.h>

#define TSEQ   2048
#define BATCH  4
#define NHEAD  16
#define HDIM   64
#define EMB    1024
#define MROWS  (TSEQ * BATCH)   // 8192
#define QKV_N  (3 * EMB)        // 3072
#define SCALE_Q 0.125f          // 64^-0.5

typedef __bf16  bf16x8 __attribute__((ext_vector_type(8)));
typedef short   s16x8  __attribute__((ext_vector_type(8)));
typedef float   f32x4  __attribute__((ext_vector_type(4)));

__device__ __forceinline__ uint16_t f2b(float f) {
    union { float f; uint32_t u; } c; c.f = f;
    uint32_t u = c.u;
    uint32_t r = (u + 0x7FFFu + ((u >> 16) & 1u)) >> 16;
    return (uint16_t)r;
}
__device__ __forceinline__ float b2f(uint16_t v) {
    union { uint32_t u; float f; } c; c.u = ((uint32_t)v) << 16;
    return c.f;
}
__device__ __forceinline__ bf16x8 ldfrag(const uint16_t* p) {
    return __builtin_bit_cast(bf16x8, *(const s16x8*)p);
}
__device__ __forceinline__ f32x4 MFMA(bf16x8 a, bf16x8 b, f32x4 c) {
    return __builtin_amdgcn_mfma_f32_16x16x32_bf16(a, b, c, 0, 0, 0);
}

#define GLOAD_LDS16(g, l) \
    __builtin_amdgcn_global_load_lds((const __attribute__((address_space(1))) void*)(g), \
                                     (__attribute__((address_space(3))) void*)(l), 16, 0, 0)

// ---------------------------------------------------------------------------
// fp32 -> bf16 conversion, 4 elements / thread
__global__ void cvt_f2b4(const float* __restrict__ src, uint16_t* __restrict__ dst, int n4) {
    int i = blockIdx.x * blockDim.x + threadIdx.x;
    if (i >= n4) return;
    float4 v = ((const float4*)src)[i];
    ushort4 o;
    o.x = f2b(v.x); o.y = f2b(v.y); o.z = f2b(v.z); o.w = f2b(v.w);
    ((ushort4*)dst)[i] = o;
}

// Build fused QKV weight [3072][1024] bf16 (+ bias f32[3072]); q part pre-scaled.
__global__ void cvt_wqkv(const float* __restrict__ Wq, const float* __restrict__ Wk,
                         const float* __restrict__ Wv, const float* __restrict__ bq,
                         const float* __restrict__ bk, const float* __restrict__ bv,
                         uint16_t* __restrict__ Wqkv, float* __restrict__ bqkv, int n4) {
    int i = blockIdx.x * blockDim.x + threadIdx.x;
    if (i < QKV_N) {
        float bval;
        if (i < EMB)            bval = bq[i] * SCALE_Q;
        else if (i < 2 * EMB)   bval = bk[i - EMB];
        else                    bval = bv[i - 2 * EMB];
        bqkv[i] = bval;
    }
    if (i >= n4) return;
    int e = i * 4;
    int n = e >> 10;          // output row 0..3071
    int k = e & 1023;
    const float* src; float sc;
    if (n < EMB)            { src = Wq + ((size_t)n << 10) + k;             sc = SCALE_Q; }
    else if (n < 2 * EMB)   { src = Wk + ((size_t)(n - EMB) << 10) + k;     sc = 1.f; }
    else                    { src = Wv + ((size_t)(n - 2 * EMB) << 10) + k; sc = 1.f; }
    float4 v = *(const float4*)src;
    ushort4 o;
    o.x = f2b(v.x * sc); o.y = f2b(v.y * sc); o.z = f2b(v.z * sc); o.w = f2b(v.w * sc);
    ((ushort4*)Wqkv)[i] = o;
}

// ---------------------------------------------------------------------------
// GEMM: C[M][N] = A[M][K] * Bt[N][K]^T + bias.  A,Bt bf16 row-major.
// m97 structure: 128x128 tile, BK=32, 256 thr (4 waves 2x2 of 64x64),
// global_load_lds width-16 staging, mfma 16x16x32 bf16.
template <typename CT>
__global__ __launch_bounds__(256) void gemm_bt(
        const uint16_t* __restrict__ A, const uint16_t* __restrict__ Bt,
        const float* __restrict__ bias, CT* __restrict__ C,
        int M, int N, int K, int tiles_n) {
    __shared__ uint16_t As[128 * 32];
    __shared__ uint16_t Bs[128 * 32];

    const int bid = blockIdx.x;
    const int tm = bid / tiles_n, tn = bid % tiles_n;
    const int tid = threadIdx.x;
    const int l = tid & 63, w = tid >> 6;
    const int wm = w >> 1, wn = w & 1;
    const int fr = l & 15, fq = l >> 4;

    f32x4 acc[4][4] = {};

    const int row_a = tid >> 2;            // 0..63
    const int kblk  = (tid & 3) << 3;      // 0,8,16,24
    const uint16_t* gA0 = A  + (size_t)(tm * 128 + row_a) * K + kblk;
    const uint16_t* gB0 = Bt + (size_t)(tn * 128 + row_a) * K + kblk;
    const uint16_t* gA1 = gA0 + (size_t)64 * K;
    const uint16_t* gB1 = gB0 + (size_t)64 * K;
    uint16_t* lA0 = As + w * 512;          // per-wave uniform LDS dest
    uint16_t* lA1 = As + 2048 + w * 512;
    uint16_t* lB0 = Bs + w * 512;
    uint16_t* lB1 = Bs + 2048 + w * 512;

    for (int k0 = 0; k0 < K; k0 += 32) {
        GLOAD_LDS16(gA0 + k0, lA0);
        GLOAD_LDS16(gA1 + k0, lA1);
        GLOAD_LDS16(gB0 + k0, lB0);
        GLOAD_LDS16(gB1 + k0, lB1);
        __syncthreads();

        bf16x8 a[4], b[4];
#pragma unroll
        for (int i = 0; i < 4; i++)
            a[i] = ldfrag(&As[(wm * 64 + i * 16 + fr) * 32 + fq * 8]);
#pragma unroll
        for (int i = 0; i < 4; i++)
            b[i] = ldfrag(&Bs[(wn * 64 + i * 16 + fr) * 32 + fq * 8]);
#pragma unroll
        for (int i = 0; i < 4; i++)
#pragma unroll
            for (int j = 0; j < 4; j++)
                acc[i][j] = MFMA(a[i], b[j], acc[i][j]);
        __syncthreads();
    }

#pragma unroll
    for (int j = 0; j < 4; j++) {
        const int col = tn * 128 + wn * 64 + j * 16 + fr;
        const float bv = bias[col];
#pragma unroll
        for (int i = 0; i < 4; i++) {
#pragma unroll
            for (int r = 0; r < 4; r++) {
                const int row = tm * 128 + wm * 64 + i * 16 + fq * 4 + r;
                const float v = acc[i][j][r] + bv;
                if constexpr (sizeof(CT) == 2) C[(size_t)row * N + col] = (CT)f2b(v);
                else                           C[(size_t)row * N + col] = (CT)v;
            }
        }
    }
}

// ---------------------------------------------------------------------------
// Flash attention fwd. qkv: [8192][3072] bf16 rows m = t*4+b, cols h*64+d (+0/+1024/+2048).
// Output attn: [8192][1024] bf16 (same [T,B,E] layout as reference pre-Wo).
// One block per (head, 64-row q tile); 4 waves x 16 q rows. KV tiles of 64.
__global__ __launch_bounds__(256) void flash_attn(
        const uint16_t* __restrict__ qkv, uint16_t* __restrict__ attnb) {
    __shared__ uint16_t Qs[64][72];
    __shared__ uint16_t Ks[64][72];
    __shared__ uint16_t Vt[64][72];       // V transposed: Vt[d][t]
    __shared__ uint16_t Ps[4][16][72];    // per-wave P tile

    const int bid  = blockIdx.x;
    const int head = bid >> 5;            // 0..63
    const int qt   = bid & 31;            // 0..31
    const int b    = head >> 4, h = head & 15;
    const int tid  = threadIdx.x;
    const int l = tid & 63, w = tid >> 6;
    const int fr = l & 15, fq = l >> 4;
    const int qcol = h * 64;

    // load Q tile [64][64]
#pragma unroll
    for (int rep = 0; rep < 2; rep++) {
        int row = rep * 32 + (tid >> 3);
        int c = (tid & 7) * 8;
        int t = qt * 64 + row;
        const uint16_t* src = qkv + ((size_t)t * BATCH + b) * QKV_N + qcol + c;
        *(uint4*)&Qs[row][c] = *(const uint4*)src;
    }
    __syncthreads();

    bf16x8 aq0 = ldfrag(&Qs[w * 16 + fr][fq * 8]);
    bf16x8 aq1 = ldfrag(&Qs[w * 16 + fr][32 + fq * 8]);

    float mrun[4], lrun[4];
    f32x4 of[4] = {};
#pragma unroll
    for (int j = 0; j < 4; j++) { mrun[j] = -1e30f; lrun[j] = 0.f; }

    for (int kt = 0; kt < TSEQ / 64; kt++) {
        // stage K tile and transposed V tile
#pragma unroll
        for (int rep = 0; rep < 2; rep++) {
            int row = rep * 32 + (tid >> 3);
            int c = (tid & 7) * 8;
            int t = kt * 64 + row;
            const uint16_t* kp = qkv + ((size_t)t * BATCH + b) * QKV_N + EMB + qcol + c;
            *(uint4*)&Ks[row][c] = *(const uint4*)kp;
            uint4 vv = *(const uint4*)(kp + EMB);
            const uint16_t* ve = (const uint16_t*)&vv;
#pragma unroll
            for (int j = 0; j < 8; j++) Vt[c + j][row] = ve[j];
        }
        __syncthreads();

        // S = Q K^T  (16 q rows x 64 k cols per wave)
        f32x4 sf[4];
#pragma unroll
        for (int tb = 0; tb < 4; tb++) {
            bf16x8 b0 = ldfrag(&Ks[tb * 16 + fr][fq * 8]);
            bf16x8 b1 = ldfrag(&Ks[tb * 16 + fr][32 + fq * 8]);
            f32x4 s = {0.f, 0.f, 0.f, 0.f};
            s = MFMA(aq0, b0, s);
            s = MFMA(aq1, b1, s);
            sf[tb] = s;
        }

        // online softmax (lane owns rows fq*4+j, one col per frag)
#pragma unroll
        for (int j = 0; j < 4; j++) {
            float mx = fmaxf(fmaxf(sf[0][j], sf[1][j]), fmaxf(sf[2][j], sf[3][j]));
#pragma unroll
            for (int off = 1; off < 16; off <<= 1) mx = fmaxf(mx, __shfl_xor(mx, off));
            float mnew = fmaxf(mrun[j], mx);
            float scale = __expf(mrun[j] - mnew);
            mrun[j] = mnew;
            float rs = 0.f;
#pragma unroll
            for (int tb = 0; tb < 4; tb++) {
                float p = __expf(sf[tb][j] - mnew);
                uint16_t pb = f2b(p);
                Ps[w][fq * 4 + j][tb * 16 + fr] = pb;
                rs += b2f(pb);
            }
#pragma unroll
            for (int off = 1; off < 16; off <<= 1) rs += __shfl_xor(rs, off);
            lrun[j] = lrun[j] * scale + rs;
#pragma unroll
            for (int df = 0; df < 4; df++) of[df][j] *= scale;
        }

        // O += P V   (P from per-wave LDS, V^T from LDS)
        bf16x8 ap0 = ldfrag(&Ps[w][fr][fq * 8]);
        bf16x8 ap1 = ldfrag(&Ps[w][fr][32 + fq * 8]);
#pragma unroll
        for (int df = 0; df < 4; df++) {
            bf16x8 bv0 = ldfrag(&Vt[df * 16 + fr][fq * 8]);
            bf16x8 bv1 = ldfrag(&Vt[df * 16 + fr][32 + fq * 8]);
            of[df] = MFMA(ap0, bv0, of[df]);
            of[df] = MFMA(ap1, bv1, of[df]);
        }
        __syncthreads();
    }

    // normalize + store
#pragma unroll
    for (int df = 0; df < 4; df++) {
        const int col = h * 64 + df * 16 + fr;
#pragma unroll
        for (int j = 0; j < 4; j++) {
            const int t = qt * 64 + w * 16 + fq * 4 + j;
            const float v = of[df][j] / lrun[j];
            attnb[((size_t)t * BATCH + b) * EMB + col] = f2b(v);
        }
    }
}

// ---------------------------------------------------------------------------
extern "C" void kernel_launch(void* const* d_in, const int* in_sizes, int n_in,
                              void* d_out, int out_size, void* d_ws, size_t ws_size,
                              hipStream_t stream) {
    const float* X  = (const float*)d_in[0];
    const float* Wq = (const float*)d_in[1];
    const float* bq = (const float*)d_in[2];
    const float* Wk = (const float*)d_in[3];
    const float* bk = (const float*)d_in[4];
    const float* Wv = (const float*)d_in[5];
    const float* bv = (const float*)d_in[6];
    const float* Wo = (const float*)d_in[7];
    const float* bo = (const float*)d_in[8];
    float* out = (float*)d_out;

    uint8_t* ws = (uint8_t*)d_ws;
    uint16_t* Xbf   = (uint16_t*)(ws);                  // 8192*1024*2  = 16,777,216
    uint16_t* Wqkv  = (uint16_t*)(ws + 16777216);       // 3072*1024*2  =  6,291,456
    uint16_t* Wobf  = (uint16_t*)(ws + 23068672);       // 1024*1024*2  =  2,097,152
    float*    bqkv  = (float*)   (ws + 25165824);       // 3072*4       =     12,288
    uint16_t* qkv   = (uint16_t*)(ws + 25178112);       // 8192*3072*2  = 50,331,648
    uint16_t* attnb = (uint16_t*)(ws + 75509760);       // 8192*1024*2  = 16,777,216
    // total = 92,286,976 bytes

    cvt_f2b4<<<(MROWS * EMB / 4 + 255) / 256, 256, 0, stream>>>(X, Xbf, MROWS * EMB / 4);
    cvt_f2b4<<<(EMB * EMB / 4 + 255) / 256, 256, 0, stream>>>(Wo, Wobf, EMB * EMB / 4);
    cvt_wqkv<<<(QKV_N * EMB / 4 + 255) / 256, 256, 0, stream>>>(
        Wq, Wk, Wv, bq, bk, bv, Wqkv, bqkv, QKV_N * EMB / 4);

    gemm_bt<uint16_t><<<(MROWS / 128) * (QKV_N / 128), 256, 0, stream>>>(
        Xbf, Wqkv, bqkv, qkv, MROWS, QKV_N, EMB, QKV_N / 128);

    flash_attn<<<64 * (TSEQ / 64), 256, 0, stream>>>(qkv, attnb);

    gemm_bt<float><<<(MROWS / 128) * (EMB / 128), 256, 0, stream>>>(
        attnb, Wobf, bo, out, MROWS, EMB, EMB, EMB / 128);
}

// Round 2
// 245.199 us; speedup vs baseline: 1.8333x; 1.8333x over previous
//
#include <hip/hip_runtime.h>
#include <stdint.h>

#define TSEQ   2048
#define BATCH  4
#define NHEAD  16
#define HDIM   64
#define EMB    1024
#define MROWS  (TSEQ * BATCH)   // 8192
#define QKV_N  (3 * EMB)        // 3072
#define SCALE_Q 0.125f          // 64^-0.5

typedef __bf16  bf16x8  __attribute__((ext_vector_type(8)));
typedef short   s16x8   __attribute__((ext_vector_type(8)));
typedef float   f32x4   __attribute__((ext_vector_type(4)));
typedef float   f32x16  __attribute__((ext_vector_type(16)));

__device__ __forceinline__ uint16_t f2b(float f) {
    union { float f; uint32_t u; } c; c.f = f;
    uint32_t u = c.u;
    uint32_t r = (u + 0x7FFFu + ((u >> 16) & 1u)) >> 16;
    return (uint16_t)r;
}
__device__ __forceinline__ float b2f(uint16_t v) {
    union { uint32_t u; float f; } c; c.u = ((uint32_t)v) << 16;
    return c.f;
}
__device__ __forceinline__ bf16x8 ldfrag(const uint16_t* p) {
    return __builtin_bit_cast(bf16x8, *(const s16x8*)p);
}
__device__ __forceinline__ f32x4 MFMA(bf16x8 a, bf16x8 b, f32x4 c) {
    return __builtin_amdgcn_mfma_f32_16x16x32_bf16(a, b, c, 0, 0, 0);
}
__device__ __forceinline__ f32x16 MFMA32(bf16x8 a, bf16x8 b, f32x16 c) {
    return __builtin_amdgcn_mfma_f32_32x32x16_bf16(a, b, c, 0, 0, 0);
}

#define GLOAD_LDS16(g, l) \
    __builtin_amdgcn_global_load_lds((const __attribute__((address_space(1))) void*)(g), \
                                     (__attribute__((address_space(3))) void*)(l), 16, 0, 0)

// ---------------------------------------------------------------------------
// fp32 -> bf16 conversion, 4 elements / thread
__global__ void cvt_f2b4(const float* __restrict__ src, uint16_t* __restrict__ dst, int n4) {
    int i = blockIdx.x * blockDim.x + threadIdx.x;
    if (i >= n4) return;
    float4 v = ((const float4*)src)[i];
    ushort4 o;
    o.x = f2b(v.x); o.y = f2b(v.y); o.z = f2b(v.z); o.w = f2b(v.w);
    ((ushort4*)dst)[i] = o;
}

// Build fused QKV weight [3072][1024] bf16 (+ bias f32[3072]); q part pre-scaled.
__global__ void cvt_wqkv(const float* __restrict__ Wq, const float* __restrict__ Wk,
                         const float* __restrict__ Wv, const float* __restrict__ bq,
                         const float* __restrict__ bk, const float* __restrict__ bv,
                         uint16_t* __restrict__ Wqkv, float* __restrict__ bqkv, int n4) {
    int i = blockIdx.x * blockDim.x + threadIdx.x;
    if (i < QKV_N) {
        float bval;
        if (i < EMB)            bval = bq[i] * SCALE_Q;
        else if (i < 2 * EMB)   bval = bk[i - EMB];
        else                    bval = bv[i - 2 * EMB];
        bqkv[i] = bval;
    }
    if (i >= n4) return;
    int e = i * 4;
    int n = e >> 10;          // output row 0..3071
    int k = e & 1023;
    const float* src; float sc;
    if (n < EMB)            { src = Wq + ((size_t)n << 10) + k;             sc = SCALE_Q; }
    else if (n < 2 * EMB)   { src = Wk + ((size_t)(n - EMB) << 10) + k;     sc = 1.f; }
    else                    { src = Wv + ((size_t)(n - 2 * EMB) << 10) + k; sc = 1.f; }
    float4 v = *(const float4*)src;
    ushort4 o;
    o.x = f2b(v.x * sc); o.y = f2b(v.y * sc); o.z = f2b(v.z * sc); o.w = f2b(v.w * sc);
    ((ushort4*)Wqkv)[i] = o;
}

// ---------------------------------------------------------------------------
// GEMM: C[M][N] = A[M][K] * Bt[N][K]^T + bias.  A,Bt bf16 row-major.
template <typename CT>
__global__ __launch_bounds__(256) void gemm_bt(
        const uint16_t* __restrict__ A, const uint16_t* __restrict__ Bt,
        const float* __restrict__ bias, CT* __restrict__ C,
        int M, int N, int K, int tiles_n) {
    __shared__ uint16_t As[128 * 32];
    __shared__ uint16_t Bs[128 * 32];

    const int bid = blockIdx.x;
    const int tm = bid / tiles_n, tn = bid % tiles_n;
    const int tid = threadIdx.x;
    const int l = tid & 63, w = tid >> 6;
    const int wm = w >> 1, wn = w & 1;
    const int fr = l & 15, fq = l >> 4;

    f32x4 acc[4][4] = {};

    const int row_a = tid >> 2;            // 0..63
    const int kblk  = (tid & 3) << 3;      // 0,8,16,24
    const uint16_t* gA0 = A  + (size_t)(tm * 128 + row_a) * K + kblk;
    const uint16_t* gB0 = Bt + (size_t)(tn * 128 + row_a) * K + kblk;
    const uint16_t* gA1 = gA0 + (size_t)64 * K;
    const uint16_t* gB1 = gB0 + (size_t)64 * K;
    uint16_t* lA0 = As + w * 512;          // per-wave uniform LDS dest
    uint16_t* lA1 = As + 2048 + w * 512;
    uint16_t* lB0 = Bs + w * 512;
    uint16_t* lB1 = Bs + 2048 + w * 512;

    for (int k0 = 0; k0 < K; k0 += 32) {
        GLOAD_LDS16(gA0 + k0, lA0);
        GLOAD_LDS16(gA1 + k0, lA1);
        GLOAD_LDS16(gB0 + k0, lB0);
        GLOAD_LDS16(gB1 + k0, lB1);
        __syncthreads();

        bf16x8 a[4], b[4];
#pragma unroll
        for (int i = 0; i < 4; i++)
            a[i] = ldfrag(&As[(wm * 64 + i * 16 + fr) * 32 + fq * 8]);
#pragma unroll
        for (int i = 0; i < 4; i++)
            b[i] = ldfrag(&Bs[(wn * 64 + i * 16 + fr) * 32 + fq * 8]);
#pragma unroll
        for (int i = 0; i < 4; i++)
#pragma unroll
            for (int j = 0; j < 4; j++)
                acc[i][j] = MFMA(a[i], b[j], acc[i][j]);
        __syncthreads();
    }

#pragma unroll
    for (int j = 0; j < 4; j++) {
        const int col = tn * 128 + wn * 64 + j * 16 + fr;
        const float bv = bias[col];
#pragma unroll
        for (int i = 0; i < 4; i++) {
#pragma unroll
            for (int r = 0; r < 4; r++) {
                const int row = tm * 128 + wm * 64 + i * 16 + fq * 4 + r;
                const float v = acc[i][j][r] + bv;
                if constexpr (sizeof(CT) == 2) C[(size_t)row * N + col] = (CT)f2b(v);
                else                           C[(size_t)row * N + col] = (CT)v;
            }
        }
    }
}

// ---------------------------------------------------------------------------
// Flash attention, 32x32 swapped-QK structure.
// qkv: [8192][3072] bf16, rows m = t*4+b, head cols h*64 (+0/+1024/+2048 for q/k/v).
// Output attnb: [8192][1024] bf16.
// Grid: 1024 = head(64) x qtile(16). Block: 256 thr = 4 waves; wave owns 32 q rows.
// K LDS [64 kv][64 d], Vt LDS [64 d][64 kv], both XOR-swizzled:
//   elem(row,colE) = row*64 + (colE ^ (((row&7)^((row>>3)&7))<<3))
__device__ __forceinline__ int swze(int row, int colE) {
    return (row << 6) + (colE ^ ((((row & 7) ^ ((row >> 3) & 7)) & 7) << 3));
}

__global__ __launch_bounds__(256) void flash_attn2(
        const uint16_t* __restrict__ qkv, uint16_t* __restrict__ attnb) {
    __shared__ __align__(16) uint16_t smem[16384];   // 32KB; Ks | Vt, reused as Ost
    uint16_t* Ks = smem;
    uint16_t* Vt = smem + 4096;

    const int bid  = blockIdx.x;
    const int head = bid >> 4;            // 0..63  (b*16+h)
    const int qt   = bid & 15;            // 0..15
    const int b    = head >> 4, h = head & 15;
    const int tid  = threadIdx.x;
    const int l  = tid & 63, w = tid >> 6;
    const int q5 = l & 31;                // lane's q (and kpos/d row for A-frags)
    const int hi = l >> 5;

    // ---- Q fragments (B-operand of swapped QK): Q[q5][d=16s+8hi+0..7]
    const int qrow = qt * 128 + w * 32 + q5;
    const uint16_t* qb = qkv + ((size_t)(qrow * 4 + b)) * 3072 + h * 64 + hi * 8;
    bf16x8 qf[4];
#pragma unroll
    for (int s = 0; s < 4; s++) qf[s] = ldfrag(qb + 16 * s);

    // ---- staging indices: thread covers kv-row sk, col chunk sc..sc+15
    const int sk = tid >> 2;              // 0..63
    const int sc = (tid & 3) * 16;        // 0,16,32,48
    const size_t tstep = (size_t)64 * 4 * 3072;
    const uint16_t* kvp = qkv + ((size_t)(sk * 4 + b)) * 3072 + 1024 + h * 64 + sc;

    // prologue: stage tile 0
    {
        uint4 k0 = *(const uint4*)(kvp);
        uint4 k1 = *(const uint4*)(kvp + 8);
        uint4 v0 = *(const uint4*)(kvp + 1024);
        uint4 v1 = *(const uint4*)(kvp + 1032);
        kvp += tstep;
        *(uint4*)&Ks[swze(sk, sc)]     = k0;
        *(uint4*)&Ks[swze(sk, sc + 8)] = k1;
        const uint16_t* ve0 = (const uint16_t*)&v0;
        const uint16_t* ve1 = (const uint16_t*)&v1;
#pragma unroll
        for (int j = 0; j < 8; j++) Vt[swze(sc + j, sk)]     = ve0[j];
#pragma unroll
        for (int j = 0; j < 8; j++) Vt[swze(sc + 8 + j, sk)] = ve1[j];
    }
    __syncthreads();

    f32x16 o0 = {}, o1 = {};
    float mrun = -1e30f, lrun = 0.f;

    for (int t = 0; t < 32; t++) {
        // T14: issue next tile's global loads before compute
        uint4 nk0, nk1, nv0, nv1;
        if (t < 31) {
            nk0 = *(const uint4*)(kvp);
            nk1 = *(const uint4*)(kvp + 8);
            nv0 = *(const uint4*)(kvp + 1024);
            nv1 = *(const uint4*)(kvp + 1032);
            kvp += tstep;
        }

        // ---- S^T = mfma(K, Q): C[m=kpos][n=q]; two 32-kpos tiles
        f32x16 s0 = {}, s1 = {};
#pragma unroll
        for (int s = 0; s < 4; s++) {
            bf16x8 kf0 = ldfrag(&Ks[swze(q5,      16 * s + 8 * hi)]);
            bf16x8 kf1 = ldfrag(&Ks[swze(32 + q5, 16 * s + 8 * hi)]);
            s0 = MFMA32(kf0, qf[s], s0);
            s1 = MFMA32(kf1, qf[s], s1);
        }

        // ---- online softmax, all in-lane except one cross-half shfl
        float mx = s0[0];
#pragma unroll
        for (int i = 1; i < 16; i++) mx = fmaxf(mx, s0[i]);
#pragma unroll
        for (int i = 0; i < 16; i++) mx = fmaxf(mx, s1[i]);
        mx = fmaxf(mx, __shfl_xor(mx, 32));
        if (!__all(mx <= mrun + 8.f)) {          // T13 defer-max
            float mnew = fmaxf(mrun, mx);
            float scl = __expf(mrun - mnew);
            mrun = mnew;
            lrun *= scl;
#pragma unroll
            for (int i = 0; i < 16; i++) { o0[i] *= scl; o1[i] *= scl; }
        }
        float rs = 0.f;
#pragma unroll
        for (int i = 0; i < 16; i++) { s0[i] = __expf(s0[i] - mrun); rs += s0[i]; }
#pragma unroll
        for (int i = 0; i < 16; i++) { s1[i] = __expf(s1[i] - mrun); rs += s1[i]; }
        rs += __shfl_xor(rs, 32);
        lrun += rs;

        // ---- pack P to bf16 dwords; redistribute to B-frag layout via shfl_xor(32)
        uint32_t pk[16];
#pragma unroll
        for (int rr = 0; rr < 8; rr++) {
            pk[rr]     = (uint32_t)f2b(s0[2 * rr]) | ((uint32_t)f2b(s0[2 * rr + 1]) << 16);
            pk[8 + rr] = (uint32_t)f2b(s1[2 * rr]) | ((uint32_t)f2b(s1[2 * rr + 1]) << 16);
        }
        bf16x8 pf[4];
#pragma unroll
        for (int kt = 0; kt < 4; kt++) {
            const int b0 = (kt >> 1) * 8 + (kt & 1) * 4;
            uint32_t own0 = hi ? pk[b0 + 2] : pk[b0 + 0];
            uint32_t own1 = hi ? pk[b0 + 3] : pk[b0 + 1];
            uint32_t snd0 = hi ? pk[b0 + 0] : pk[b0 + 2];
            uint32_t snd1 = hi ? pk[b0 + 1] : pk[b0 + 3];
            uint32_t rec0 = (uint32_t)__shfl_xor((int)snd0, 32);
            uint32_t rec1 = (uint32_t)__shfl_xor((int)snd1, 32);
            union { uint32_t u[4]; bf16x8 v; } cv;
            cv.u[0] = hi ? rec0 : own0;
            cv.u[1] = hi ? rec1 : own1;
            cv.u[2] = hi ? own0 : rec0;
            cv.u[3] = hi ? own1 : rec1;
            pf[kt] = cv.v;
        }

        // ---- O^T += mfma(V^T, P): C[m=d][n=q]
#pragma unroll
        for (int kt = 0; kt < 4; kt++) {
            bf16x8 vf0 = ldfrag(&Vt[swze(q5,      16 * kt + 8 * hi)]);
            bf16x8 vf1 = ldfrag(&Vt[swze(32 + q5, 16 * kt + 8 * hi)]);
            o0 = MFMA32(vf0, pf[kt], o0);
            o1 = MFMA32(vf1, pf[kt], o1);
        }

        // ---- write next tile to LDS
        if (t < 31) {
            __syncthreads();
            *(uint4*)&Ks[swze(sk, sc)]     = nk0;
            *(uint4*)&Ks[swze(sk, sc + 8)] = nk1;
            const uint16_t* ve0 = (const uint16_t*)&nv0;
            const uint16_t* ve1 = (const uint16_t*)&nv1;
#pragma unroll
            for (int j = 0; j < 8; j++) Vt[swze(sc + j, sk)]     = ve0[j];
#pragma unroll
            for (int j = 0; j < 8; j++) Vt[swze(sc + 8 + j, sk)] = ve1[j];
            __syncthreads();
        }
    }

    // ---- epilogue: O^T/l -> bf16 -> per-wave LDS stage -> coalesced store
    __syncthreads();                      // smem reuse
    const float inv = 1.f / lrun;
    uint16_t* Ost = smem + w * 2048;      // [32 q][64 d], swizzled rows
#pragma unroll
    for (int dt = 0; dt < 2; dt++) {
#pragma unroll
        for (int a = 0; a < 4; a++) {
#pragma unroll
            for (int cp = 0; cp < 2; cp++) {
                const int r = a * 4 + cp * 2;
                float va = (dt ? o1[r] : o0[r]) * inv;
                float vb = (dt ? o1[r + 1] : o0[r + 1]) * inv;
                uint32_t dw = (uint32_t)f2b(va) | ((uint32_t)f2b(vb) << 16);
                const int d0 = dt * 32 + a * 8 + hi * 4 + cp * 2;
                *(uint32_t*)&Ost[swze(q5, d0)] = dw;
            }
        }
    }
    __syncthreads();
    const int rq = l >> 1;
    const int qrow2 = qt * 128 + w * 32 + rq;
    uint16_t* ob = attnb + ((size_t)(qrow2 * 4 + b)) * 1024 + h * 64;
#pragma unroll
    for (int i = 0; i < 4; i++) {
        const int c4 = (l & 1) * 4 + i;
        uint4 vv = *(const uint4*)&Ost[swze(rq, c4 * 8)];
        *(uint4*)(ob + c4 * 8) = vv;
    }
}

// ---------------------------------------------------------------------------
extern "C" void kernel_launch(void* const* d_in, const int* in_sizes, int n_in,
                              void* d_out, int out_size, void* d_ws, size_t ws_size,
                              hipStream_t stream) {
    const float* X  = (const float*)d_in[0];
    const float* Wq = (const float*)d_in[1];
    const float* bq = (const float*)d_in[2];
    const float* Wk = (const float*)d_in[3];
    const float* bk = (const float*)d_in[4];
    const float* Wv = (const float*)d_in[5];
    const float* bv = (const float*)d_in[6];
    const float* Wo = (const float*)d_in[7];
    const float* bo = (const float*)d_in[8];
    float* out = (float*)d_out;

    uint8_t* ws = (uint8_t*)d_ws;
    uint16_t* Xbf   = (uint16_t*)(ws);                  // 8192*1024*2  = 16,777,216
    uint16_t* Wqkv  = (uint16_t*)(ws + 16777216);       // 3072*1024*2  =  6,291,456
    uint16_t* Wobf  = (uint16_t*)(ws + 23068672);       // 1024*1024*2  =  2,097,152
    float*    bqkv  = (float*)   (ws + 25165824);       // 3072*4       =     12,288
    uint16_t* qkv   = (uint16_t*)(ws + 25178112);       // 8192*3072*2  = 50,331,648
    uint16_t* attnb = (uint16_t*)(ws + 75509760);       // 8192*1024*2  = 16,777,216

    cvt_f2b4<<<(MROWS * EMB / 4 + 255) / 256, 256, 0, stream>>>(X, Xbf, MROWS * EMB / 4);
    cvt_f2b4<<<(EMB * EMB / 4 + 255) / 256, 256, 0, stream>>>(Wo, Wobf, EMB * EMB / 4);
    cvt_wqkv<<<(QKV_N * EMB / 4 + 255) / 256, 256, 0, stream>>>(
        Wq, Wk, Wv, bq, bk, bv, Wqkv, bqkv, QKV_N * EMB / 4);

    gemm_bt<uint16_t><<<(MROWS / 128) * (QKV_N / 128), 256, 0, stream>>>(
        Xbf, Wqkv, bqkv, qkv, MROWS, QKV_N, EMB, QKV_N / 128);

    flash_attn2<<<64 * 16, 256, 0, stream>>>(qkv, attnb);

    gemm_bt<float><<<(MROWS / 128) * (EMB / 128), 256, 0, stream>>>(
        attnb, Wobf, bo, out, MROWS, EMB, EMB, EMB / 128);
}

// Round 3
// 226.077 us; speedup vs baseline: 1.9884x; 1.0846x over previous
//
#include <hip/hip_runtime.h>
#include <stdint.h>

#define TSEQ   2048
#define BATCH  4
#define NHEAD  16
#define HDIM   64
#define EMB    1024
#define MROWS  (TSEQ * BATCH)   // 8192
#define QKV_N  (3 * EMB)        // 3072
#define SCALE_Q 0.125f          // 64^-0.5
#define LOG2E  1.4426950408889634f

typedef __bf16  bf16x8  __attribute__((ext_vector_type(8)));
typedef __bf16  bf16x2  __attribute__((ext_vector_type(2)));
typedef short   s16x8   __attribute__((ext_vector_type(8)));
typedef float   f32x4   __attribute__((ext_vector_type(4)));
typedef float   f32x16  __attribute__((ext_vector_type(16)));

__device__ __forceinline__ uint16_t b16c(float f) {
    __bf16 h = (__bf16)f;
    return __builtin_bit_cast(uint16_t, h);
}
__device__ __forceinline__ uint32_t pk2(float a, float b) {
    bf16x2 h; h[0] = (__bf16)a; h[1] = (__bf16)b;
    return __builtin_bit_cast(uint32_t, h);
}
__device__ __forceinline__ float exp2hw(float x) {
    float r; asm("v_exp_f32 %0, %1" : "=v"(r) : "v"(x)); return r;
}
__device__ __forceinline__ bf16x8 ldfrag(const uint16_t* p) {
    return __builtin_bit_cast(bf16x8, *(const s16x8*)p);
}
__device__ __forceinline__ f32x4 MFMA(bf16x8 a, bf16x8 b, f32x4 c) {
    return __builtin_amdgcn_mfma_f32_16x16x32_bf16(a, b, c, 0, 0, 0);
}
__device__ __forceinline__ f32x16 MFMA32(bf16x8 a, bf16x8 b, f32x16 c) {
    return __builtin_amdgcn_mfma_f32_32x32x16_bf16(a, b, c, 0, 0, 0);
}

#define GLOAD_LDS16(g, l) \
    __builtin_amdgcn_global_load_lds((const __attribute__((address_space(1))) void*)(g), \
                                     (__attribute__((address_space(3))) void*)(l), 16, 0, 0)

// ---------------------------------------------------------------------------
// fp32 -> bf16 conversion, 4 elements / thread
__global__ void cvt_f2b4(const float* __restrict__ src, uint16_t* __restrict__ dst, int n4) {
    int i = blockIdx.x * blockDim.x + threadIdx.x;
    if (i >= n4) return;
    float4 v = ((const float4*)src)[i];
    ushort4 o;
    o.x = b16c(v.x); o.y = b16c(v.y); o.z = b16c(v.z); o.w = b16c(v.w);
    ((ushort4*)dst)[i] = o;
}

// Build fused QKV weight [3072][1024] bf16 (+ bias f32[3072]); q part pre-scaled.
__global__ void cvt_wqkv(const float* __restrict__ Wq, const float* __restrict__ Wk,
                         const float* __restrict__ Wv, const float* __restrict__ bq,
                         const float* __restrict__ bk, const float* __restrict__ bv,
                         uint16_t* __restrict__ Wqkv, float* __restrict__ bqkv, int n4) {
    int i = blockIdx.x * blockDim.x + threadIdx.x;
    if (i < QKV_N) {
        float bval;
        if (i < EMB)            bval = bq[i] * SCALE_Q;
        else if (i < 2 * EMB)   bval = bk[i - EMB];
        else                    bval = bv[i - 2 * EMB];
        bqkv[i] = bval;
    }
    if (i >= n4) return;
    int e = i * 4;
    int n = e >> 10;          // output row 0..3071
    int k = e & 1023;
    const float* src; float sc;
    if (n < EMB)            { src = Wq + ((size_t)n << 10) + k;             sc = SCALE_Q; }
    else if (n < 2 * EMB)   { src = Wk + ((size_t)(n - EMB) << 10) + k;     sc = 1.f; }
    else                    { src = Wv + ((size_t)(n - 2 * EMB) << 10) + k; sc = 1.f; }
    float4 v = *(const float4*)src;
    ushort4 o;
    o.x = b16c(v.x * sc); o.y = b16c(v.y * sc); o.z = b16c(v.z * sc); o.w = b16c(v.w * sc);
    ((ushort4*)Wqkv)[i] = o;
}

// ---------------------------------------------------------------------------
// GEMM: C[M][N] = A[M][K] * Bt[N][K]^T + bias.  A,Bt bf16 row-major.
// m97 structure + T1 XCD swizzle (grid must be %8==0).
template <typename CT>
__global__ __launch_bounds__(256) void gemm_bt(
        const uint16_t* __restrict__ A, const uint16_t* __restrict__ Bt,
        const float* __restrict__ bias, CT* __restrict__ C,
        int M, int N, int K, int tiles_n) {
    __shared__ uint16_t As[128 * 32];
    __shared__ uint16_t Bs[128 * 32];

    const int nwg = gridDim.x;
    const int bid0 = blockIdx.x;
    const int bid = (bid0 & 7) * (nwg >> 3) + (bid0 >> 3);   // T1 swizzle
    const int tm = bid / tiles_n, tn = bid % tiles_n;
    const int tid = threadIdx.x;
    const int l = tid & 63, w = tid >> 6;
    const int wm = w >> 1, wn = w & 1;
    const int fr = l & 15, fq = l >> 4;

    f32x4 acc[4][4] = {};

    const int row_a = tid >> 2;            // 0..63
    const int kblk  = (tid & 3) << 3;      // 0,8,16,24
    const uint16_t* gA0 = A  + (size_t)(tm * 128 + row_a) * K + kblk;
    const uint16_t* gB0 = Bt + (size_t)(tn * 128 + row_a) * K + kblk;
    const uint16_t* gA1 = gA0 + (size_t)64 * K;
    const uint16_t* gB1 = gB0 + (size_t)64 * K;
    uint16_t* lA0 = As + w * 512;          // per-wave uniform LDS dest
    uint16_t* lA1 = As + 2048 + w * 512;
    uint16_t* lB0 = Bs + w * 512;
    uint16_t* lB1 = Bs + 2048 + w * 512;

    for (int k0 = 0; k0 < K; k0 += 32) {
        GLOAD_LDS16(gA0 + k0, lA0);
        GLOAD_LDS16(gA1 + k0, lA1);
        GLOAD_LDS16(gB0 + k0, lB0);
        GLOAD_LDS16(gB1 + k0, lB1);
        __syncthreads();

        bf16x8 a[4], b[4];
#pragma unroll
        for (int i = 0; i < 4; i++)
            a[i] = ldfrag(&As[(wm * 64 + i * 16 + fr) * 32 + fq * 8]);
#pragma unroll
        for (int i = 0; i < 4; i++)
            b[i] = ldfrag(&Bs[(wn * 64 + i * 16 + fr) * 32 + fq * 8]);
#pragma unroll
        for (int i = 0; i < 4; i++)
#pragma unroll
            for (int j = 0; j < 4; j++)
                acc[i][j] = MFMA(a[i], b[j], acc[i][j]);
        __syncthreads();
    }

#pragma unroll
    for (int j = 0; j < 4; j++) {
        const int col = tn * 128 + wn * 64 + j * 16 + fr;
        const float bv = bias[col];
#pragma unroll
        for (int i = 0; i < 4; i++) {
#pragma unroll
            for (int r = 0; r < 4; r++) {
                const int row = tm * 128 + wm * 64 + i * 16 + fq * 4 + r;
                const float v = acc[i][j][r] + bv;
                if constexpr (sizeof(CT) == 2) C[(size_t)row * N + col] = (CT)b16c(v);
                else                           C[(size_t)row * N + col] = (CT)v;
            }
        }
    }
}

// ---------------------------------------------------------------------------
// Flash attention, 32x32 swapped-QK structure.
__device__ __forceinline__ int swze(int row, int colE) {
    return (row << 6) + (colE ^ ((((row & 7) ^ ((row >> 3) & 7)) & 7) << 3));
}

__global__ __launch_bounds__(256) void flash_attn2(
        const uint16_t* __restrict__ qkv, uint16_t* __restrict__ attnb) {
    __shared__ __align__(16) uint16_t smem[16384];   // 32KB; Ks | Vt, reused as Ost
    uint16_t* Ks = smem;
    uint16_t* Vt = smem + 4096;

    int bid = (int)blockIdx.x;
    bid = ((bid & 7) << 7) + (bid >> 3);  // T1: 128 consecutive bids (8 heads) per XCD
    const int head = bid >> 4;            // 0..63  (b*16+h)
    const int qt   = bid & 15;            // 0..15
    const int b    = head >> 4, h = head & 15;
    const int tid  = threadIdx.x;
    const int l  = tid & 63, w = tid >> 6;
    const int q5 = l & 31;                // lane's q (and kpos/d row for A-frags)
    const int hi = l >> 5;

    // ---- Q fragments (B-operand of swapped QK): Q[q5][d=16s+8hi+0..7]
    const int qrow = qt * 128 + w * 32 + q5;
    const uint16_t* qb = qkv + ((size_t)(qrow * 4 + b)) * 3072 + h * 64 + hi * 8;
    bf16x8 qf[4];
#pragma unroll
    for (int s = 0; s < 4; s++) qf[s] = ldfrag(qb + 16 * s);

    // ---- staging indices: thread covers kv-row sk, col chunk sc..sc+15
    const int sk = tid >> 2;              // 0..63
    const int sc = (tid & 3) * 16;        // 0,16,32,48
    const size_t tstep = (size_t)64 * 4 * 3072;
    const uint16_t* kvp = qkv + ((size_t)(sk * 4 + b)) * 3072 + 1024 + h * 64 + sc;

    // prologue: stage tile 0
    {
        uint4 k0 = *(const uint4*)(kvp);
        uint4 k1 = *(const uint4*)(kvp + 8);
        uint4 v0 = *(const uint4*)(kvp + 1024);
        uint4 v1 = *(const uint4*)(kvp + 1032);
        kvp += tstep;
        *(uint4*)&Ks[swze(sk, sc)]     = k0;
        *(uint4*)&Ks[swze(sk, sc + 8)] = k1;
        const uint16_t* ve0 = (const uint16_t*)&v0;
        const uint16_t* ve1 = (const uint16_t*)&v1;
#pragma unroll
        for (int j = 0; j < 8; j++) Vt[swze(sc + j, sk)]     = ve0[j];
#pragma unroll
        for (int j = 0; j < 8; j++) Vt[swze(sc + 8 + j, sk)] = ve1[j];
    }
    __syncthreads();

    f32x16 o0 = {}, o1 = {};
    float mrun = -1e30f, lrun = 0.f;

    for (int t = 0; t < 32; t++) {
        // T14: issue next tile's global loads before compute
        uint4 nk0, nk1, nv0, nv1;
        if (t < 31) {
            nk0 = *(const uint4*)(kvp);
            nk1 = *(const uint4*)(kvp + 8);
            nv0 = *(const uint4*)(kvp + 1024);
            nv1 = *(const uint4*)(kvp + 1032);
            kvp += tstep;
        }

        // ---- S^T = mfma(K, Q): C[m=kpos][n=q]; two 32-kpos tiles
        f32x16 s0 = {}, s1 = {};
#pragma unroll
        for (int s = 0; s < 4; s++) {
            bf16x8 kf0 = ldfrag(&Ks[swze(q5,      16 * s + 8 * hi)]);
            bf16x8 kf1 = ldfrag(&Ks[swze(32 + q5, 16 * s + 8 * hi)]);
            s0 = MFMA32(kf0, qf[s], s0);
            s1 = MFMA32(kf1, qf[s], s1);
        }

        // ---- online softmax: ILP max tree + permlane cross-half reduce
        float t0 = s0[0], t1 = s0[1], t2 = s0[2], t3 = s0[3];
#pragma unroll
        for (int i = 4; i < 16; i += 4) {
            t0 = fmaxf(t0, s0[i]);     t1 = fmaxf(t1, s0[i + 1]);
            t2 = fmaxf(t2, s0[i + 2]); t3 = fmaxf(t3, s0[i + 3]);
        }
#pragma unroll
        for (int i = 0; i < 16; i += 4) {
            t0 = fmaxf(t0, s1[i]);     t1 = fmaxf(t1, s1[i + 1]);
            t2 = fmaxf(t2, s1[i + 2]); t3 = fmaxf(t3, s1[i + 3]);
        }
        float mx = fmaxf(fmaxf(t0, t1), fmaxf(t2, t3));
        {
            auto rm = __builtin_amdgcn_permlane32_swap(__float_as_int(mx), __float_as_int(mx), false, false);
            mx = fmaxf(__int_as_float(rm[0]), __int_as_float(rm[1]));
        }
        if (!__all(mx <= mrun + 8.f)) {          // T13 defer-max
            float mnew = fmaxf(mrun, mx);
            float scl = exp2hw((mrun - mnew) * LOG2E);
            mrun = mnew;
            lrun *= scl;
#pragma unroll
            for (int i = 0; i < 16; i++) { o0[i] *= scl; o1[i] *= scl; }
        }
        const float mm = mrun * LOG2E;
#pragma unroll
        for (int i = 0; i < 16; i++) s0[i] = exp2hw(__builtin_fmaf(s0[i], LOG2E, -mm));
#pragma unroll
        for (int i = 0; i < 16; i++) s1[i] = exp2hw(__builtin_fmaf(s1[i], LOG2E, -mm));
        float p0 = 0.f, p1 = 0.f, p2 = 0.f, p3 = 0.f;
#pragma unroll
        for (int i = 0; i < 16; i += 4) {
            p0 += s0[i]; p1 += s0[i + 1]; p2 += s0[i + 2]; p3 += s0[i + 3];
            p0 += s1[i]; p1 += s1[i + 1]; p2 += s1[i + 2]; p3 += s1[i + 3];
        }
        float rs = (p0 + p1) + (p2 + p3);
        {
            auto rr2 = __builtin_amdgcn_permlane32_swap(__float_as_int(rs), __float_as_int(rs), false, false);
            rs = __int_as_float(rr2[0]) + __int_as_float(rr2[1]);
        }
        lrun += rs;

        // ---- pack P to bf16 dwords (v_cvt_pk via compiler casts)
        uint32_t pk[16];
#pragma unroll
        for (int rr = 0; rr < 8; rr++) {
            pk[rr]     = pk2(s0[2 * rr], s0[2 * rr + 1]);
            pk[8 + rr] = pk2(s1[2 * rr], s1[2 * rr + 1]);
        }
        // ---- redistribute to B-frag layout: one permlane32_swap yields both dwords
        bf16x8 pf[4];
#pragma unroll
        for (int kt = 0; kt < 4; kt++) {
            const int b0 = (kt >> 1) * 8 + (kt & 1) * 4;
            auto r02 = __builtin_amdgcn_permlane32_swap((int)pk[b0 + 0], (int)pk[b0 + 2], false, false);
            auto r13 = __builtin_amdgcn_permlane32_swap((int)pk[b0 + 1], (int)pk[b0 + 3], false, false);
            union { uint32_t u[4]; bf16x8 v; } cv;
            cv.u[0] = (uint32_t)r02[0]; cv.u[1] = (uint32_t)r13[0];
            cv.u[2] = (uint32_t)r02[1]; cv.u[3] = (uint32_t)r13[1];
            pf[kt] = cv.v;
        }

        // ---- O^T += mfma(V^T, P): C[m=d][n=q]
#pragma unroll
        for (int kt = 0; kt < 4; kt++) {
            bf16x8 vf0 = ldfrag(&Vt[swze(q5,      16 * kt + 8 * hi)]);
            bf16x8 vf1 = ldfrag(&Vt[swze(32 + q5, 16 * kt + 8 * hi)]);
            o0 = MFMA32(vf0, pf[kt], o0);
            o1 = MFMA32(vf1, pf[kt], o1);
        }

        // ---- write next tile to LDS
        if (t < 31) {
            __syncthreads();
            *(uint4*)&Ks[swze(sk, sc)]     = nk0;
            *(uint4*)&Ks[swze(sk, sc + 8)] = nk1;
            const uint16_t* ve0 = (const uint16_t*)&nv0;
            const uint16_t* ve1 = (const uint16_t*)&nv1;
#pragma unroll
            for (int j = 0; j < 8; j++) Vt[swze(sc + j, sk)]     = ve0[j];
#pragma unroll
            for (int j = 0; j < 8; j++) Vt[swze(sc + 8 + j, sk)] = ve1[j];
            __syncthreads();
        }
    }

    // ---- epilogue: O^T/l -> bf16 -> per-wave LDS stage -> coalesced store
    __syncthreads();                      // smem reuse
    const float inv = 1.f / lrun;
    uint16_t* Ost = smem + w * 2048;      // [32 q][64 d], swizzled rows
#pragma unroll
    for (int dt = 0; dt < 2; dt++) {
#pragma unroll
        for (int a = 0; a < 4; a++) {
#pragma unroll
            for (int cp = 0; cp < 2; cp++) {
                const int r = a * 4 + cp * 2;
                float va = (dt ? o1[r] : o0[r]) * inv;
                float vb = (dt ? o1[r + 1] : o0[r + 1]) * inv;
                uint32_t dw = pk2(va, vb);
                const int d0 = dt * 32 + a * 8 + hi * 4 + cp * 2;
                *(uint32_t*)&Ost[swze(q5, d0)] = dw;
            }
        }
    }
    __syncthreads();
    const int rq = l >> 1;
    const int qrow2 = qt * 128 + w * 32 + rq;
    uint16_t* ob = attnb + ((size_t)(qrow2 * 4 + b)) * 1024 + h * 64;
#pragma unroll
    for (int i = 0; i < 4; i++) {
        const int c4 = (l & 1) * 4 + i;
        uint4 vv = *(const uint4*)&Ost[swze(rq, c4 * 8)];
        *(uint4*)(ob + c4 * 8) = vv;
    }
}

// ---------------------------------------------------------------------------
extern "C" void kernel_launch(void* const* d_in, const int* in_sizes, int n_in,
                              void* d_out, int out_size, void* d_ws, size_t ws_size,
                              hipStream_t stream) {
    const float* X  = (const float*)d_in[0];
    const float* Wq = (const float*)d_in[1];
    const float* bq = (const float*)d_in[2];
    const float* Wk = (const float*)d_in[3];
    const float* bk = (const float*)d_in[4];
    const float* Wv = (const float*)d_in[5];
    const float* bv = (const float*)d_in[6];
    const float* Wo = (const float*)d_in[7];
    const float* bo = (const float*)d_in[8];
    float* out = (float*)d_out;

    uint8_t* ws = (uint8_t*)d_ws;
    uint16_t* Xbf   = (uint16_t*)(ws);                  // 8192*1024*2  = 16,777,216
    uint16_t* Wqkv  = (uint16_t*)(ws + 16777216);       // 3072*1024*2  =  6,291,456
    uint16_t* Wobf  = (uint16_t*)(ws + 23068672);       // 1024*1024*2  =  2,097,152
    float*    bqkv  = (float*)   (ws + 25165824);       // 3072*4       =     12,288
    uint16_t* qkv   = (uint16_t*)(ws + 25178112);       // 8192*3072*2  = 50,331,648
    uint16_t* attnb = (uint16_t*)(ws + 75509760);       // 8192*1024*2  = 16,777,216

    cvt_f2b4<<<(MROWS * EMB / 4 + 255) / 256, 256, 0, stream>>>(X, Xbf, MROWS * EMB / 4);
    cvt_f2b4<<<(EMB * EMB / 4 + 255) / 256, 256, 0, stream>>>(Wo, Wobf, EMB * EMB / 4);
    cvt_wqkv<<<(QKV_N * EMB / 4 + 255) / 256, 256, 0, stream>>>(
        Wq, Wk, Wv, bq, bk, bv, Wqkv, bqkv, QKV_N * EMB / 4);

    gemm_bt<uint16_t><<<(MROWS / 128) * (QKV_N / 128), 256, 0, stream>>>(
        Xbf, Wqkv, bqkv, qkv, MROWS, QKV_N, EMB, QKV_N / 128);

    flash_attn2<<<64 * 16, 256, 0, stream>>>(qkv, attnb);

    gemm_bt<float><<<(MROWS / 128) * (EMB / 128), 256, 0, stream>>>(
        attnb, Wobf, bo, out, MROWS, EMB, EMB, EMB / 128);
}

// Round 4
// 218.595 us; speedup vs baseline: 2.0564x; 1.0342x over previous
//
#include <hip/hip_runtime.h>
#include <stdint.h>

#define TSEQ   2048
#define BATCH  4
#define NHEAD  16
#define HDIM   64
#define EMB    1024
#define MROWS  (TSEQ * BATCH)   // 8192
#define QKV_N  (3 * EMB)        // 3072
#define SCALE_Q 0.125f          // 64^-0.5
#define LOG2E  1.4426950408889634f

typedef __bf16  bf16x8  __attribute__((ext_vector_type(8)));
typedef __bf16  bf16x2  __attribute__((ext_vector_type(2)));
typedef short   s16x8   __attribute__((ext_vector_type(8)));
typedef float   f32x4   __attribute__((ext_vector_type(4)));
typedef float   f32x16  __attribute__((ext_vector_type(16)));

__device__ __forceinline__ uint16_t b16c(float f) {
    __bf16 h = (__bf16)f;
    return __builtin_bit_cast(uint16_t, h);
}
__device__ __forceinline__ uint32_t pk2(float a, float b) {
    bf16x2 h; h[0] = (__bf16)a; h[1] = (__bf16)b;
    return __builtin_bit_cast(uint32_t, h);
}
__device__ __forceinline__ float exp2hw(float x) {
    float r; asm("v_exp_f32 %0, %1" : "=v"(r) : "v"(x)); return r;
}
__device__ __forceinline__ bf16x8 ldfrag(const uint16_t* p) {
    return __builtin_bit_cast(bf16x8, *(const s16x8*)p);
}
__device__ __forceinline__ f32x4 MFMA(bf16x8 a, bf16x8 b, f32x4 c) {
    return __builtin_amdgcn_mfma_f32_16x16x32_bf16(a, b, c, 0, 0, 0);
}
__device__ __forceinline__ f32x16 MFMA32(bf16x8 a, bf16x8 b, f32x16 c) {
    return __builtin_amdgcn_mfma_f32_32x32x16_bf16(a, b, c, 0, 0, 0);
}

#define GLOAD_LDS16(g, l) \
    __builtin_amdgcn_global_load_lds((const __attribute__((address_space(1))) void*)(g), \
                                     (__attribute__((address_space(3))) void*)(l), 16, 0, 0)

// ---------------------------------------------------------------------------
// fp32 -> bf16 conversion, 4 elements / thread
__global__ void cvt_f2b4(const float* __restrict__ src, uint16_t* __restrict__ dst, int n4) {
    int i = blockIdx.x * blockDim.x + threadIdx.x;
    if (i >= n4) return;
    float4 v = ((const float4*)src)[i];
    ushort4 o;
    o.x = b16c(v.x); o.y = b16c(v.y); o.z = b16c(v.z); o.w = b16c(v.w);
    ((ushort4*)dst)[i] = o;
}

// Build fused QKV weight [3072][1024] bf16 (+ bias f32[3072]); q part pre-scaled.
__global__ void cvt_wqkv(const float* __restrict__ Wq, const float* __restrict__ Wk,
                         const float* __restrict__ Wv, const float* __restrict__ bq,
                         const float* __restrict__ bk, const float* __restrict__ bv,
                         uint16_t* __restrict__ Wqkv, float* __restrict__ bqkv, int n4) {
    int i = blockIdx.x * blockDim.x + threadIdx.x;
    if (i < QKV_N) {
        float bval;
        if (i < EMB)            bval = bq[i] * SCALE_Q;
        else if (i < 2 * EMB)   bval = bk[i - EMB];
        else                    bval = bv[i - 2 * EMB];
        bqkv[i] = bval;
    }
    if (i >= n4) return;
    int e = i * 4;
    int n = e >> 10;          // output row 0..3071
    int k = e & 1023;
    const float* src; float sc;
    if (n < EMB)            { src = Wq + ((size_t)n << 10) + k;             sc = SCALE_Q; }
    else if (n < 2 * EMB)   { src = Wk + ((size_t)(n - EMB) << 10) + k;     sc = 1.f; }
    else                    { src = Wv + ((size_t)(n - 2 * EMB) << 10) + k; sc = 1.f; }
    float4 v = *(const float4*)src;
    ushort4 o;
    o.x = b16c(v.x * sc); o.y = b16c(v.y * sc); o.z = b16c(v.z * sc); o.w = b16c(v.w * sc);
    ((ushort4*)Wqkv)[i] = o;
}

// ---------------------------------------------------------------------------
// GEMM: C[M][N] = A[M][K] * Bt[N][K]^T + bias.  A,Bt bf16 row-major.
// m97 structure + T1 XCD swizzle (grid must be %8==0).
template <typename CT>
__global__ __launch_bounds__(256) void gemm_bt(
        const uint16_t* __restrict__ A, const uint16_t* __restrict__ Bt,
        const float* __restrict__ bias, CT* __restrict__ C,
        int M, int N, int K, int tiles_n) {
    __shared__ uint16_t As[128 * 32];
    __shared__ uint16_t Bs[128 * 32];

    const int nwg = gridDim.x;
    const int bid0 = blockIdx.x;
    const int bid = (bid0 & 7) * (nwg >> 3) + (bid0 >> 3);   // T1 swizzle
    const int tm = bid / tiles_n, tn = bid % tiles_n;
    const int tid = threadIdx.x;
    const int l = tid & 63, w = tid >> 6;
    const int wm = w >> 1, wn = w & 1;
    const int fr = l & 15, fq = l >> 4;

    f32x4 acc[4][4] = {};

    const int row_a = tid >> 2;            // 0..63
    const int kblk  = (tid & 3) << 3;      // 0,8,16,24
    const uint16_t* gA0 = A  + (size_t)(tm * 128 + row_a) * K + kblk;
    const uint16_t* gB0 = Bt + (size_t)(tn * 128 + row_a) * K + kblk;
    const uint16_t* gA1 = gA0 + (size_t)64 * K;
    const uint16_t* gB1 = gB0 + (size_t)64 * K;
    uint16_t* lA0 = As + w * 512;          // per-wave uniform LDS dest
    uint16_t* lA1 = As + 2048 + w * 512;
    uint16_t* lB0 = Bs + w * 512;
    uint16_t* lB1 = Bs + 2048 + w * 512;

    for (int k0 = 0; k0 < K; k0 += 32) {
        GLOAD_LDS16(gA0 + k0, lA0);
        GLOAD_LDS16(gA1 + k0, lA1);
        GLOAD_LDS16(gB0 + k0, lB0);
        GLOAD_LDS16(gB1 + k0, lB1);
        __syncthreads();

        bf16x8 a[4], b[4];
#pragma unroll
        for (int i = 0; i < 4; i++)
            a[i] = ldfrag(&As[(wm * 64 + i * 16 + fr) * 32 + fq * 8]);
#pragma unroll
        for (int i = 0; i < 4; i++)
            b[i] = ldfrag(&Bs[(wn * 64 + i * 16 + fr) * 32 + fq * 8]);
#pragma unroll
        for (int i = 0; i < 4; i++)
#pragma unroll
            for (int j = 0; j < 4; j++)
                acc[i][j] = MFMA(a[i], b[j], acc[i][j]);
        __syncthreads();
    }

#pragma unroll
    for (int j = 0; j < 4; j++) {
        const int col = tn * 128 + wn * 64 + j * 16 + fr;
        const float bv = bias[col];
#pragma unroll
        for (int i = 0; i < 4; i++) {
#pragma unroll
            for (int r = 0; r < 4; r++) {
                const int row = tm * 128 + wm * 64 + i * 16 + fq * 4 + r;
                const float v = acc[i][j][r] + bv;
                if constexpr (sizeof(CT) == 2) C[(size_t)row * N + col] = (CT)b16c(v);
                else                           C[(size_t)row * N + col] = (CT)v;
            }
        }
    }
}

// ---------------------------------------------------------------------------
// Flash attention v3: 32x32 swapped-QK, 64 q-rows per wave (256 q per block),
// K staged via global_load_lds (inverse-swizzled source), V reg-staged with
// paired b32 writes, true double-buffer, one barrier per tile.
__device__ __forceinline__ int swze(int row, int colE) {
    return (row << 6) + (colE ^ ((((row & 7) ^ ((row >> 3) & 7)) & 7) << 3));
}

__device__ __forceinline__ void softmax_half(
        f32x16& s0, f32x16& s1, float& mrun, float& lrun,
        f32x16& oa, f32x16& ob, bf16x8* pf) {
    float t0 = s0[0], t1 = s0[1], t2 = s0[2], t3 = s0[3];
#pragma unroll
    for (int i = 4; i < 16; i += 4) {
        t0 = fmaxf(t0, s0[i]);     t1 = fmaxf(t1, s0[i + 1]);
        t2 = fmaxf(t2, s0[i + 2]); t3 = fmaxf(t3, s0[i + 3]);
    }
#pragma unroll
    for (int i = 0; i < 16; i += 4) {
        t0 = fmaxf(t0, s1[i]);     t1 = fmaxf(t1, s1[i + 1]);
        t2 = fmaxf(t2, s1[i + 2]); t3 = fmaxf(t3, s1[i + 3]);
    }
    float mx = fmaxf(fmaxf(t0, t1), fmaxf(t2, t3));
    {
        auto rm = __builtin_amdgcn_permlane32_swap(__float_as_int(mx), __float_as_int(mx), false, false);
        mx = fmaxf(__int_as_float(rm[0]), __int_as_float(rm[1]));
    }
    if (!__all(mx <= mrun + 8.f)) {          // T13 defer-max
        float mnew = fmaxf(mrun, mx);
        float scl = exp2hw((mrun - mnew) * LOG2E);
        mrun = mnew;
        lrun *= scl;
#pragma unroll
        for (int i = 0; i < 16; i++) { oa[i] *= scl; ob[i] *= scl; }
    }
    const float mm = mrun * LOG2E;
#pragma unroll
    for (int i = 0; i < 16; i++) s0[i] = exp2hw(__builtin_fmaf(s0[i], LOG2E, -mm));
#pragma unroll
    for (int i = 0; i < 16; i++) s1[i] = exp2hw(__builtin_fmaf(s1[i], LOG2E, -mm));
    float p0 = 0.f, p1 = 0.f, p2 = 0.f, p3 = 0.f;
#pragma unroll
    for (int i = 0; i < 16; i += 4) {
        p0 += s0[i]; p1 += s0[i + 1]; p2 += s0[i + 2]; p3 += s0[i + 3];
        p0 += s1[i]; p1 += s1[i + 1]; p2 += s1[i + 2]; p3 += s1[i + 3];
    }
    float rs = (p0 + p1) + (p2 + p3);
    {
        auto rr2 = __builtin_amdgcn_permlane32_swap(__float_as_int(rs), __float_as_int(rs), false, false);
        rs = __int_as_float(rr2[0]) + __int_as_float(rr2[1]);
    }
    lrun += rs;

    uint32_t pk[16];
#pragma unroll
    for (int rr = 0; rr < 8; rr++) {
        pk[rr]     = pk2(s0[2 * rr], s0[2 * rr + 1]);
        pk[8 + rr] = pk2(s1[2 * rr], s1[2 * rr + 1]);
    }
#pragma unroll
    for (int kt = 0; kt < 4; kt++) {
        const int b0 = (kt >> 1) * 8 + (kt & 1) * 4;
        auto r02 = __builtin_amdgcn_permlane32_swap((int)pk[b0 + 0], (int)pk[b0 + 2], false, false);
        auto r13 = __builtin_amdgcn_permlane32_swap((int)pk[b0 + 1], (int)pk[b0 + 3], false, false);
        union { uint32_t u[4]; bf16x8 v; } cv;
        cv.u[0] = (uint32_t)r02[0]; cv.u[1] = (uint32_t)r13[0];
        cv.u[2] = (uint32_t)r02[1]; cv.u[3] = (uint32_t)r13[1];
        pf[kt] = cv.v;
    }
}

__global__ __launch_bounds__(256, 2) void flash_attn3(
        const uint16_t* __restrict__ qkv, uint16_t* __restrict__ attnb) {
    __shared__ __align__(16) uint16_t smem[16384];   // 32KB: K0|K1|V0|V1 (4096 elems each)
    uint16_t* k0p = smem;
    uint16_t* k1p = smem + 4096;
    uint16_t* v0p = smem + 8192;
    uint16_t* v1p = smem + 12288;

    int bid = (int)blockIdx.x;
    bid = (bid & 7) * 64 + (bid >> 3);    // T1: 64 consecutive (8 heads) per XCD
    const int head = bid >> 3;            // 0..63  (b*16+h)
    const int qt   = bid & 7;             // 0..7 (256 q rows each)
    const int b    = head >> 4, h = head & 15;
    const int tid  = threadIdx.x;
    const int l  = tid & 63, w = tid >> 6;
    const int q5 = l & 31;
    const int hi = l >> 5;
    const size_t tstep = (size_t)64 * 4 * 3072;

    // ---- Q fragments, two q-halves (B-operand of swapped QK)
    const int qrowA = qt * 256 + w * 64 + q5;
    const uint16_t* qbA = qkv + ((size_t)(qrowA * 4 + b)) * 3072 + h * 64 + hi * 8;
    const uint16_t* qbB = qbA + (size_t)32 * 4 * 3072;
    bf16x8 qA[4], qB[4];
#pragma unroll
    for (int s = 0; s < 4; s++) { qA[s] = ldfrag(qbA + 16 * s); qB[s] = ldfrag(qbB + 16 * s); }

    // ---- K DMA per-lane source (inverse swizzle): wave w stages rows 16w..16w+15
    const int r0 = w * 16 + (l >> 3);
    const int r1 = r0 + 8;
    const int cu0 = (((l & 7) ^ ((r0 & 7) ^ ((r0 >> 3) & 7))) & 7) << 3;
    const int cu1 = (((l & 7) ^ ((r1 & 7) ^ ((r1 >> 3) & 7))) & 7) << 3;
    const uint16_t* gk0 = qkv + ((size_t)(r0 * 4 + b)) * 3072 + 1024 + h * 64 + cu0;
    const uint16_t* gk1 = qkv + ((size_t)(r1 * 4 + b)) * 3072 + 1024 + h * 64 + cu1;
    const int kdst0 = w * 1024;           // elem offset into K buffer
    const int kdst1 = w * 1024 + 512;

    // ---- V staging: thread covers kv rows skv,skv+1 x d cols scol..scol+7
    const int skv  = (tid >> 3) * 2;
    const int scol = (tid & 7) * 8;
    const uint16_t* gv = qkv + ((size_t)(skv * 4 + b)) * 3072 + 2048 + h * 64 + scol;
    int voff[8];
#pragma unroll
    for (int j2 = 0; j2 < 8; j2++)
        voff[j2] = (scol + j2) * 64 + (skv ^ ((((j2 ^ (scol >> 3)) & 7)) << 3));

    // ---- prologue: stage tile 0 into buf0
    GLOAD_LDS16(gk0, k0p + kdst0);
    GLOAD_LDS16(gk1, k0p + kdst1);
    {
        uint4 a0 = *(const uint4*)gv;
        uint4 a1 = *(const uint4*)(gv + 12288);
        const uint16_t* e0 = (const uint16_t*)&a0;
        const uint16_t* e1 = (const uint16_t*)&a1;
#pragma unroll
        for (int j2 = 0; j2 < 8; j2++)
            *(uint32_t*)&v0p[voff[j2]] = (uint32_t)e0[j2] | ((uint32_t)e1[j2] << 16);
    }
    gk0 += tstep; gk1 += tstep; gv += tstep;
    __syncthreads();

    f32x16 o0 = {}, o1 = {}, o2 = {}, o3 = {};
    float mrunA = -1e30f, lrunA = 0.f, mrunB = -1e30f, lrunB = 0.f;

    for (int t = 0; t < 32; t++) {
        const uint16_t* kb = (t & 1) ? k1p : k0p;
        const uint16_t* vb = (t & 1) ? v1p : v0p;
        uint16_t* kn = (t & 1) ? k0p : k1p;
        uint16_t* vn = (t & 1) ? v0p : v1p;

        // prefetch next tile: K by DMA, V into regs
        uint4 a0, a1;
        if (t < 31) {
            GLOAD_LDS16(gk0, kn + kdst0);
            GLOAD_LDS16(gk1, kn + kdst1);
            a0 = *(const uint4*)gv;
            a1 = *(const uint4*)(gv + 12288);
            gk0 += tstep; gk1 += tstep; gv += tstep;
        }

        // ---- S^T = mfma(K, Q) for both q-halves (K frags shared)
        f32x16 sA0 = {}, sA1 = {}, sB0 = {}, sB1 = {};
#pragma unroll
        for (int s = 0; s < 4; s++) {
            bf16x8 kf0 = ldfrag(&kb[swze(q5,      16 * s + 8 * hi)]);
            bf16x8 kf1 = ldfrag(&kb[swze(32 + q5, 16 * s + 8 * hi)]);
            sA0 = MFMA32(kf0, qA[s], sA0);
            sA1 = MFMA32(kf1, qA[s], sA1);
            sB0 = MFMA32(kf0, qB[s], sB0);
            sB1 = MFMA32(kf1, qB[s], sB1);
        }

        bf16x8 pfA[4], pfB[4];
        softmax_half(sA0, sA1, mrunA, lrunA, o0, o1, pfA);
        softmax_half(sB0, sB1, mrunB, lrunB, o2, o3, pfB);

        // ---- O^T += mfma(V^T, P): V frags shared across halves
#pragma unroll
        for (int kt = 0; kt < 4; kt++) {
            bf16x8 vf0 = ldfrag(&vb[swze(q5,      16 * kt + 8 * hi)]);
            bf16x8 vf1 = ldfrag(&vb[swze(32 + q5, 16 * kt + 8 * hi)]);
            o0 = MFMA32(vf0, pfA[kt], o0);
            o1 = MFMA32(vf1, pfA[kt], o1);
            o2 = MFMA32(vf0, pfB[kt], o2);
            o3 = MFMA32(vf1, pfB[kt], o3);
        }

        // ---- commit prefetched V to buf^1
        if (t < 31) {
            const uint16_t* e0 = (const uint16_t*)&a0;
            const uint16_t* e1 = (const uint16_t*)&a1;
#pragma unroll
            for (int j2 = 0; j2 < 8; j2++)
                *(uint32_t*)&vn[voff[j2]] = (uint32_t)e0[j2] | ((uint32_t)e1[j2] << 16);
        }
        __syncthreads();
    }

    // ---- epilogue: both q-halves via per-wave LDS stage (disjoint regions)
    uint16_t* OstA = smem + w * 4096;
    uint16_t* OstB = OstA + 2048;
#pragma unroll
    for (int half = 0; half < 2; half++) {
        uint16_t* Ost = half ? OstB : OstA;
        const float inv = 1.f / (half ? lrunB : lrunA);
#pragma unroll
        for (int dt = 0; dt < 2; dt++) {
            const f32x16& ov = half ? (dt ? o3 : o2) : (dt ? o1 : o0);
#pragma unroll
            for (int a = 0; a < 4; a++) {
#pragma unroll
                for (int cp = 0; cp < 2; cp++) {
                    const int r = a * 4 + cp * 2;
                    uint32_t dw = pk2(ov[r] * inv, ov[r + 1] * inv);
                    const int d0 = dt * 32 + a * 8 + hi * 4 + cp * 2;
                    *(uint32_t*)&Ost[swze(q5, d0)] = dw;
                }
            }
        }
    }
    const int rq = l >> 1;
#pragma unroll
    for (int half = 0; half < 2; half++) {
        uint16_t* Ost = half ? OstB : OstA;
        const int qrow2 = qt * 256 + w * 64 + half * 32 + rq;
        uint16_t* ob = attnb + ((size_t)(qrow2 * 4 + b)) * 1024 + h * 64;
#pragma unroll
        for (int i = 0; i < 4; i++) {
            const int c4 = (l & 1) * 4 + i;
            uint4 vv = *(const uint4*)&Ost[swze(rq, c4 * 8)];
            *(uint4*)(ob + c4 * 8) = vv;
        }
    }
}

// ---------------------------------------------------------------------------
extern "C" void kernel_launch(void* const* d_in, const int* in_sizes, int n_in,
                              void* d_out, int out_size, void* d_ws, size_t ws_size,
                              hipStream_t stream) {
    const float* X  = (const float*)d_in[0];
    const float* Wq = (const float*)d_in[1];
    const float* bq = (const float*)d_in[2];
    const float* Wk = (const float*)d_in[3];
    const float* bk = (const float*)d_in[4];
    const float* Wv = (const float*)d_in[5];
    const float* bv = (const float*)d_in[6];
    const float* Wo = (const float*)d_in[7];
    const float* bo = (const float*)d_in[8];
    float* out = (float*)d_out;

    uint8_t* ws = (uint8_t*)d_ws;
    uint16_t* Xbf   = (uint16_t*)(ws);                  // 8192*1024*2  = 16,777,216
    uint16_t* Wqkv  = (uint16_t*)(ws + 16777216);       // 3072*1024*2  =  6,291,456
    uint16_t* Wobf  = (uint16_t*)(ws + 23068672);       // 1024*1024*2  =  2,097,152
    float*    bqkv  = (float*)   (ws + 25165824);       // 3072*4       =     12,288
    uint16_t* qkv   = (uint16_t*)(ws + 25178112);       // 8192*3072*2  = 50,331,648
    uint16_t* attnb = (uint16_t*)(ws + 75509760);       // 8192*1024*2  = 16,777,216

    cvt_f2b4<<<(MROWS * EMB / 4 + 255) / 256, 256, 0, stream>>>(X, Xbf, MROWS * EMB / 4);
    cvt_f2b4<<<(EMB * EMB / 4 + 255) / 256, 256, 0, stream>>>(Wo, Wobf, EMB * EMB / 4);
    cvt_wqkv<<<(QKV_N * EMB / 4 + 255) / 256, 256, 0, stream>>>(
        Wq, Wk, Wv, bq, bk, bv, Wqkv, bqkv, QKV_N * EMB / 4);

    gemm_bt<uint16_t><<<(MROWS / 128) * (QKV_N / 128), 256, 0, stream>>>(
        Xbf, Wqkv, bqkv, qkv, MROWS, QKV_N, EMB, QKV_N / 128);

    flash_attn3<<<512, 256, 0, stream>>>(qkv, attnb);

    gemm_bt<float><<<(MROWS / 128) * (EMB / 128), 256, 0, stream>>>(
        attnb, Wobf, bo, out, MROWS, EMB, EMB, EMB / 128);
}